// Round 4
// baseline (344.095 us; speedup 1.0000x reference)
//
#include <hip/hip_runtime.h>
#include <hip/hip_bf16.h>

// BLSTM: B=1024, T=512, V=128, H=128, HH=64, gates=256/dir.
// R20: wave-autonomous recurrence — the barrier and the LDS round-trip are
// REMOVED from the serial chain (R19 proved the chain, not issue, is the
// limit: 4 fixes = 0 delta at 743 cyc/step).
//   Each wave owns 2 batch-row recurrences end-to-end. A (16xK) = 2 real
//   rows x8 dup (A[row]=h[row>>3]); B = all 256 gates as 16 N-tiles
//   (4 gates x 4 j-slices) x 2 K-chunks -> 32 MFMAs/step/wave, B-frags
//   persistent in 128 VGPRs. C layout gives lane l BOTH its gate sets
//   lane-locally: (r=l>>5, j=l&31) via tiles n'={q&1}, and (r, j+32) via
//   n'={2+(q&1)} — one cndmask per gate, acc reg [0] uniformly.
//   h-exchange for next step's A-frags is all in-wave:
//     2x mov_dpp(lane^1) + 2x v_cvt_pk_bf16_f32 (RNE, bit-identical to the
//     old LDS bf16 path) + 8x ds_bpermute (even source lanes only, so odd
//     lanes' packs are dead) -> two bf16x8 A-frags. No s_barrier anywhere
//     in the loop; no inter-wave coupling.
//   1024 independent waves = 256 blocks (4 waves) = 1 block/CU, 1 wave/SIMD.
// Math bit-identical to R17/R19 (same K order, z4 C-in, post-MFMA x-add,
// RNE h): absmax oracle must stay EXACTLY 9.766e-4.

#define T_STEPS 512
#define BATCH   1024
#define VOCAB   128
#define HID     128
#define HH      64
#define NG      256
#define XPITCH  520    // 512 steps + 8 zero guard elems at the high end

#define L2E  1.4426950408889634f
#define L2E2 2.8853900817779268f

typedef __attribute__((ext_vector_type(8))) short bf16x8;
typedef __attribute__((ext_vector_type(4))) float f32x4;
typedef __attribute__((ext_vector_type(4))) int   i32x4;
typedef unsigned int  u32;
typedef unsigned short u16;

__device__ __forceinline__ float sigmoid_f(float x) {
    return __builtin_amdgcn_rcpf(1.0f + __builtin_amdgcn_exp2f(-x * L2E));
}
__device__ __forceinline__ float tanh_f(float x) {
    return 1.0f - 2.0f * __builtin_amdgcn_rcpf(1.0f + __builtin_amdgcn_exp2f(x * L2E2));
}
__device__ __forceinline__ u16 f2bf_rne(float f) {
    u32 u = __builtin_bit_cast(u32, f);
    u += 0x7FFFu + ((u >> 16) & 1u);
    return (u16)(u >> 16);
}
// lane^1 swap via DPP quad_perm [1,0,3,2] (VALU, no LDS)
__device__ __forceinline__ float dpp_swap1(float v) {
    int i = __builtin_bit_cast(int, v);
    i = __builtin_amdgcn_mov_dpp(i, 0xB1, 0xF, 0xF, true);
    return __builtin_bit_cast(float, i);
}

// ---------------- Kernel 1: tab build + W_hh bf16 convert (fused) ----------
// tab3 layout: [d][v][j][4] = dot(emb[v], W_ih_d[g*64+j]) for g=i,f,g,o.
__global__ __launch_bounds__(256) void build_tab_kernel(
    const float* __restrict__ emb,
    const float* __restrict__ W_ih_f,
    const float* __restrict__ W_ih_b,
    const float* __restrict__ W_hh_f,
    const float* __restrict__ W_hh_b,
    float* __restrict__ tab3,
    u16*   __restrict__ whh_bf)
{
    int v = blockIdx.x, d = blockIdx.y, tid = threadIdx.x;
    int j = tid >> 2, g = tid & 3;
    int gr = g * HH + j;                      // W_ih gate row
    const float* W = d ? W_ih_b : W_ih_f;
    const float4* e4 = (const float4*)(emb + v * HID);
    const float4* w4 = (const float4*)(W + gr * HID);
    float acc = 0.0f;
#pragma unroll
    for (int k = 0; k < HID / 4; ++k) {
        float4 e = e4[k]; float4 w = w4[k];
        acc += e.x * w.x + e.y * w.y + e.z * w.z + e.w * w.w;
    }
    tab3[(d * VOCAB + v) * NG + j * 4 + g] = acc;

    // fused W_hh convert: plain row-major [2][256][64]
    if (tid < 128) {
        const float* Whh = d ? W_hh_b : W_hh_f;
        int idx = v * 128 + tid;              // 0..16383 within this dir
        whh_bf[d * NG * HH + idx] = f2bf_rne(Whh[idx]);
    }
}

// ---------------- Kernel 2: MFMA recurrence (wave-autonomous) -------------
// grid (128,2), block 256 (4 waves), 1 block/CU, 1 wave/SIMD.
__global__ __launch_bounds__(256, 1) void lstm_rec_kernel(
    const int*  __restrict__ x,        // [1024][512]
    const u16*  __restrict__ whh_bf,   // [2][256][64] bf16 bits
    const float* __restrict__ tab3,    // [2][128][64][4] floats
    float* __restrict__ hfin)          // [2][1024][64]
{
    __shared__ __align__(16) u32 xsT[8][XPITCH];    // dir-reversed, 16640 B

    const int tid  = threadIdx.x;
    const int lane = tid & 63;
    const int wave = tid >> 6;           // 0..3
    const int q    = lane >> 4;          // 0..3
    const int m    = lane & 15;
    const int dir    = blockIdx.y;
    const int b_base = blockIdx.x * 8;

    // stage x pre-scaled to tab3 byte offset (v<<10), dir-REVERSED so the
    // main loop always walks ascending for both directions.
    for (int i = tid; i < 8 * T_STEPS; i += 256) {
        int bl = i >> 9, t = i & (T_STEPS - 1);
        int ts = dir ? (T_STEPS - 1 - t) : t;
        xsT[bl][ts] = ((u32)x[(b_base + bl) * T_STEPS + t]) << 10;
    }
    if (tid < 64)                         // zero guards [512..519] x 8 rows
        xsT[tid >> 3][T_STEPS + (tid & 7)] = 0;

    // persistent B-fragments: tile (g, n') covers gates g*64 + n'*16 + col.
    // lane(q,m): B[k=q*8+i+32c][col=m] = W_hh[g*64+n'*16+m][q*8+i+32c]
    const u16* WB = whh_bf + dir * NG * HH;
    bf16x8 Bg[4][4][2];
#pragma unroll
    for (int g = 0; g < 4; ++g)
#pragma unroll
        for (int n = 0; n < 4; ++n)
#pragma unroll
            for (int c = 0; c < 2; ++c)
                Bg[g][n][c] = *(const bf16x8*)(WB + (g * 64 + n * 16 + m) * HH
                                                  + c * 32 + q * 8);

    const char* tabB = (const char*)tab3 + (size_t)dir * VOCAB * NG * 4;
    const int r     = lane >> 5;                 // my batch row (of wave's 2)
    const int j0    = lane & 31;                 // my low hidden index
    const u32 joff  = (u32)j0 << 4;              // j0*16 bytes into tab row
    const int myrow = wave * 2 + r;              // xsT row
    const int addrB = ((m >> 3) << 7) | (q << 5);  // bperm base byte addr

    const f32x4 z4 = {0.f, 0.f, 0.f, 0.f};
    float cc0 = 0.f, cc1 = 0.f, h0 = 0.f, h1 = 0.f;

    __syncthreads();   // xsT staged (only sync in the kernel)

    int4 qA = *(const int4*)&xsT[myrow][0];
    int4 qB = *(const int4*)&xsT[myrow][4];
    float4 XA0 = *(const float4*)(tabB + (u32)qA.x + joff);        // step 0
    float4 XA1 = *(const float4*)(tabB + (u32)qA.x + joff + 512);
    float4 XB0, XB1;

    auto stepf = [&](const float4 Xc0, const float4 Xc1,
                     float4& Xn0, float4& Xn1, u32 e) {
        // ---- in-wave h exchange -> A-frags (prev step's h)
        float h0n = dpp_swap1(h0);
        float h1n = dpp_swap1(h1);
        u32 P0, P1;   // RNE packed (h[r][2p], h[r][2p+1]) on EVEN lanes
        asm("v_cvt_pk_bf16_f32 %0, %1, %2" : "=v"(P0) : "v"(h0), "v"(h0n));
        asm("v_cvt_pk_bf16_f32 %0, %1, %2" : "=v"(P1) : "v"(h1), "v"(h1n));
        int a0 = __builtin_amdgcn_ds_bpermute(addrB,      __builtin_bit_cast(int, P0));
        int a1 = __builtin_amdgcn_ds_bpermute(addrB + 8,  __builtin_bit_cast(int, P0));
        int a2 = __builtin_amdgcn_ds_bpermute(addrB + 16, __builtin_bit_cast(int, P0));
        int a3 = __builtin_amdgcn_ds_bpermute(addrB + 24, __builtin_bit_cast(int, P0));
        int b0 = __builtin_amdgcn_ds_bpermute(addrB,      __builtin_bit_cast(int, P1));
        int b1 = __builtin_amdgcn_ds_bpermute(addrB + 8,  __builtin_bit_cast(int, P1));
        int b2 = __builtin_amdgcn_ds_bpermute(addrB + 16, __builtin_bit_cast(int, P1));
        int b3 = __builtin_amdgcn_ds_bpermute(addrB + 24, __builtin_bit_cast(int, P1));
        i32x4 va = {a0, a1, a2, a3};
        i32x4 vb = {b0, b1, b2, b3};
        bf16x8 A0 = __builtin_bit_cast(bf16x8, va);   // k 0..31
        bf16x8 A1 = __builtin_bit_cast(bf16x8, vb);   // k 32..63

        // ---- x-term prefetch for next step (vmcnt wait lands at next use)
        Xn0 = *(const float4*)(tabB + e + joff);
        Xn1 = *(const float4*)(tabB + e + joff + 512);

        // ---- 16 gate tiles, K=64 (chunk0 sweep then chunk1 sweep)
        f32x4 acc[4][4];
#pragma unroll
        for (int g = 0; g < 4; ++g)
#pragma unroll
            for (int n = 0; n < 4; ++n)
                acc[g][n] = __builtin_amdgcn_mfma_f32_16x16x32_bf16(
                    A0, Bg[g][n][0], z4, 0, 0, 0);
#pragma unroll
        for (int g = 0; g < 4; ++g)
#pragma unroll
            for (int n = 0; n < 4; ++n)
                acc[g][n] = __builtin_amdgcn_mfma_f32_16x16x32_bf16(
                    A1, Bg[g][n][1], acc[g][n], 0, 0, 0);

        // ---- lane-local gates: reg[0] row = q*4 -> real row q>>1 == r
        const bool s = (q & 1);   // n' select for my j0 / j1
        float gi0 = (s ? acc[0][1][0] : acc[0][0][0]) + Xc0.x;
        float gf0 = (s ? acc[1][1][0] : acc[1][0][0]) + Xc0.y;
        float gg0 = (s ? acc[2][1][0] : acc[2][0][0]) + Xc0.z;
        float go0 = (s ? acc[3][1][0] : acc[3][0][0]) + Xc0.w;
        float gi1 = (s ? acc[0][3][0] : acc[0][2][0]) + Xc1.x;
        float gf1 = (s ? acc[1][3][0] : acc[1][2][0]) + Xc1.y;
        float gg1 = (s ? acc[2][3][0] : acc[2][2][0]) + Xc1.z;
        float go1 = (s ? acc[3][3][0] : acc[3][2][0]) + Xc1.w;

        // ---- two independent nonlinear chains
        cc0 = sigmoid_f(gf0) * cc0 + sigmoid_f(gi0) * tanh_f(gg0);
        h0  = sigmoid_f(go0) * tanh_f(cc0);
        cc1 = sigmoid_f(gf1) * cc1 + sigmoid_f(gi1) * tanh_f(gg1);
        h1  = sigmoid_f(go1) * tanh_f(cc1);
    };

    for (int kk = 0; kk < T_STEPS / 8; ++kk) {
        stepf(XA0, XA1, XB0, XB1, (u32)qA.y);
        stepf(XB0, XB1, XA0, XA1, (u32)qA.z);
        stepf(XA0, XA1, XB0, XB1, (u32)qA.w);
        qA = *(const int4*)&xsT[myrow][8 * kk + 8];    // steps 8kk+8..11
        stepf(XB0, XB1, XA0, XA1, (u32)qB.x);
        stepf(XA0, XA1, XB0, XB1, (u32)qB.y);
        stepf(XB0, XB1, XA0, XA1, (u32)qB.z);
        stepf(XA0, XA1, XB0, XB1, (u32)qB.w);
        qB = *(const int4*)&xsT[myrow][8 * kk + 12];   // steps 8kk+12..15
        stepf(XB0, XB1, XA0, XA1, (u32)qA.x);
    }

    // lane l owns (b_base+myrow, j0) and (b_base+myrow, j0+32)
    {
        float* dst = hfin + ((size_t)dir * BATCH + b_base + myrow) * HH;
        dst[j0]      = h0;
        dst[j0 + 32] = h1;
    }
}

// ---------------- Kernel 3: final FC (W_fc in LDS, 8 rows/block) ----------
__global__ __launch_bounds__(256) void fc_kernel(
    const float* __restrict__ hfin,    // [2][1024][64]
    const float* __restrict__ W_fc,    // [128][128]
    const float* __restrict__ b_fc,    // [128]
    float* __restrict__ out)           // [1024][128]
{
    __shared__ float wfc[HID * 129];   // row-padded: bank stride 129
    __shared__ float hid[8][HID];
    const int tid = threadIdx.x;
    const int b0  = blockIdx.x * 8;

    for (int i = tid; i < HID * HID; i += 256) {
        int r = i >> 7, c = i & 127;
        wfc[r * 129 + c] = W_fc[i];
    }
    for (int i = tid; i < 8 * HID; i += 256) {
        int bb = i >> 7, v = i & 127;
        hid[bb][v] = (v < HH) ? hfin[(0 * BATCH + b0 + bb) * HH + v]
                              : hfin[(1 * BATCH + b0 + bb) * HH + (v - HH)];
    }
    __syncthreads();

    const int v  = tid & 127;
    const int bs = (tid >> 7) * 4;     // rows [bs, bs+4)
    const float bias = b_fc[v];
    const float* wrow = wfc + v * 129;
#pragma unroll
    for (int r = 0; r < 4; ++r) {
        const float* h = hid[bs + r];
        float acc = bias;
#pragma unroll
        for (int k = 0; k < HID; k += 4) {
            acc += wrow[k]     * h[k]     + wrow[k + 1] * h[k + 1]
                 + wrow[k + 2] * h[k + 2] + wrow[k + 3] * h[k + 3];
        }
        out[(b0 + bs + r) * HID + v] = acc;
    }
}

extern "C" void kernel_launch(void* const* d_in, const int* in_sizes, int n_in,
                              void* d_out, int out_size, void* d_ws, size_t ws_size,
                              hipStream_t stream) {
    const int*   x      = (const int*)d_in[0];
    // d_in[1] = lengths : unused by the reference
    const float* emb    = (const float*)d_in[2];
    const float* W_ih_f = (const float*)d_in[3];
    const float* W_hh_f = (const float*)d_in[4];
    const float* W_ih_b = (const float*)d_in[5];
    const float* W_hh_b = (const float*)d_in[6];
    const float* W_fc   = (const float*)d_in[7];
    const float* b_fc   = (const float*)d_in[8];
    float* out = (float*)d_out;

    float* tab3   = (float*)d_ws;                         // 65536 f32
    u16*   whh_bf = (u16*)(tab3 + 2 * VOCAB * NG);        // 32768 u16
    float* hfin   = (float*)(whh_bf + 2 * NG * HH);       // 131072 f32

    build_tab_kernel<<<dim3(VOCAB, 2), 256, 0, stream>>>(
        emb, W_ih_f, W_ih_b, W_hh_f, W_hh_b, tab3, whh_bf);
    lstm_rec_kernel<<<dim3(BATCH / 8, 2), 256, 0, stream>>>(x, whh_bf, tab3, hfin);
    fc_kernel<<<dim3(BATCH / 8), 256, 0, stream>>>(hfin, W_fc, b_fc, out);
}

// Round 5
// 278.428 us; speedup vs baseline: 1.2358x; 1.2358x over previous
//
#include <hip/hip_runtime.h>
#include <hip/hip_bf16.h>

// BLSTM: B=1024, T=512, V=128, H=128, HH=64, gates=256/dir.
// R21: four independent 2-wave barrier groups per CU.
//   History: R16 (one 8-wave group/CU) 252us -> R17 (two 4-wave groups) 156us.
//   R18/R20 (1 stream/SIMD) both regressed -> the lever is INDEPENDENT
//   barrier groups per SIMD, not in-stream ILP. Extrapolate: MB=2 rows,
//   128-thread blocks, 1024 blocks, 4 blocks/CU -> every SIMD's 2 waves
//   come from DIFFERENT barrier groups by construction; barrier width 2.
//   A-tile = 2 real rows dup x8 (A[m]=h[m>>3]); each wave covers 32 j via
//   two n-tiles; lane(q,m) output = (row q>>1, j = wave*32+(q&1)*16+m) —
//   one cndmask per gate keeps 1 output/lane (trans packing optimal).
//   16 MFMA/wave/step (4 gates x 2 n-tiles x 2 K-chunks), B-frags 64 VGPR.
// Carried from R19: pitch-80 hbuf (0 conflicts), dir-reversed x staging +
// int4 offset reads, v_cvt_pk_bf16_f32 RNE h, setprio head/tail.
// Math bit-identical to R17/R19 (same K order, z4 C-in, post-MFMA x-add,
// RNE h): absmax oracle must stay EXACTLY 9.766e-4.

#define T_STEPS 512
#define BATCH   1024
#define VOCAB   128
#define HID     128
#define HH      64
#define NG      256
#define MB      2      // real batch rows per block (dup x8 in M)
#define XPITCH  520    // 512 steps + 8 zero guard elems at the high end

#define L2E  1.4426950408889634f
#define L2E2 2.8853900817779268f

typedef __attribute__((ext_vector_type(8))) short bf16x8;
typedef __attribute__((ext_vector_type(4))) float f32x4;
typedef unsigned int  u32;
typedef unsigned short u16;

__device__ __forceinline__ float sigmoid_f(float x) {
    return __builtin_amdgcn_rcpf(1.0f + __builtin_amdgcn_exp2f(-x * L2E));
}
__device__ __forceinline__ float tanh_f(float x) {
    return 1.0f - 2.0f * __builtin_amdgcn_rcpf(1.0f + __builtin_amdgcn_exp2f(x * L2E2));
}
__device__ __forceinline__ u16 f2bf_rne(float f) {
    u32 u = __builtin_bit_cast(u32, f);
    u += 0x7FFFu + ((u >> 16) & 1u);
    return (u16)(u >> 16);
}
// barrier with LDS-only drain: global (tab) prefetch loads are NOT drained —
// their vmcnt wait lands at the use point.
__device__ __forceinline__ void barrier_lgkm() {
    asm volatile("s_waitcnt lgkmcnt(0)\n\ts_barrier" ::: "memory");
}

// ---------------- Kernel 1: tab build + W_hh bf16 convert (fused) ----------
// tab3 layout: [d][v][j][4] = dot(emb[v], W_ih_d[g*64+j]) for g=i,f,g,o.
__global__ __launch_bounds__(256) void build_tab_kernel(
    const float* __restrict__ emb,
    const float* __restrict__ W_ih_f,
    const float* __restrict__ W_ih_b,
    const float* __restrict__ W_hh_f,
    const float* __restrict__ W_hh_b,
    float* __restrict__ tab3,
    u16*   __restrict__ whh_bf)
{
    int v = blockIdx.x, d = blockIdx.y, tid = threadIdx.x;
    int j = tid >> 2, g = tid & 3;
    int gr = g * HH + j;                      // W_ih gate row
    const float* W = d ? W_ih_b : W_ih_f;
    const float4* e4 = (const float4*)(emb + v * HID);
    const float4* w4 = (const float4*)(W + gr * HID);
    float acc = 0.0f;
#pragma unroll
    for (int k = 0; k < HID / 4; ++k) {
        float4 e = e4[k]; float4 w = w4[k];
        acc += e.x * w.x + e.y * w.y + e.z * w.z + e.w * w.w;
    }
    tab3[(d * VOCAB + v) * NG + j * 4 + g] = acc;

    // fused W_hh convert: plain row-major [2][256][64]
    if (tid < 128) {
        const float* Whh = d ? W_hh_b : W_hh_f;
        int idx = v * 128 + tid;              // 0..16383 within this dir
        whh_bf[d * NG * HH + idx] = f2bf_rne(Whh[idx]);
    }
}

// ---------------- Kernel 2: MFMA recurrence ----------------
// grid (512,2), block 128 (2 waves), 4 blocks/CU.
__global__ __launch_bounds__(128, 2) void lstm_rec_kernel(
    const int*  __restrict__ x,        // [1024][512]
    const u16*  __restrict__ whh_bf,   // [2][256][64] bf16 bits
    const float* __restrict__ tab3,    // [2][128][64][4] floats
    float* __restrict__ hfin)          // [2][1024][64]
{
    __shared__ __align__(16) u32 xsT[MB][XPITCH];    // dir-reversed, 4160 B
    __shared__ __align__(16) u16 hbuf[2][MB][80];    // [pp][row][80], 640 B

    const int tid  = threadIdx.x;
    const int lane = tid & 63;
    const int wave = tid >> 6;           // 0..1
    const int q    = lane >> 4;          // 0..3
    const int m    = lane & 15;
    const int dir    = blockIdx.y;
    const int b_base = blockIdx.x * MB;

    // stage x pre-scaled to tab3 byte offset (v<<10), dir-REVERSED so the
    // main loop always walks ascending for both directions.
    for (int i = tid; i < MB * T_STEPS; i += 128) {
        int bl = i >> 9, t = i & (T_STEPS - 1);
        int ts = dir ? (T_STEPS - 1 - t) : t;
        xsT[bl][ts] = ((u32)x[(b_base + bl) * T_STEPS + t]) << 10;
    }
    if (tid < MB * 8)                     // zero guards [512..519] x 2 rows
        xsT[tid >> 3][T_STEPS + (tid & 7)] = 0;
    for (int i = tid; i < (int)(sizeof(hbuf) / 4); i += 128)
        ((u32*)hbuf)[i] = 0;

    // persistent B-fragments: tile (g,n) covers gate rows
    // g*64 + wave*32 + n*16 + m ; per-lane 8 k at c*32 + q*8.
    const u16* WB = whh_bf + dir * NG * HH;
    bf16x8 Bg[4][2][2];
#pragma unroll
    for (int g = 0; g < 4; ++g)
#pragma unroll
        for (int n = 0; n < 2; ++n)
#pragma unroll
            for (int c = 0; c < 2; ++c)
                Bg[g][n][c] = *(const bf16x8*)(
                    WB + (g * 64 + wave * 32 + n * 16 + m) * HH + c * 32 + q * 8);

    const char* tabB = (const char*)tab3 + (size_t)dir * VOCAB * NG * 4;
    const int r    = q >> 1;                           // my batch row (0..1)
    const int jj   = wave * 32 + (q & 1) * 16 + m;     // my hidden index
    const u32 joff = (u32)jj << 4;                     // j*16 bytes
    const int aoff = (m >> 3) * 80 + q * 8;            // A-frag read (u16)
    const int woff = r * 80 + jj;                      // h write (u16)

    const f32x4 z4 = {0.f, 0.f, 0.f, 0.f};             // loop-invariant C-in
    float cc = 0.f, hcur = 0.f;

    __syncthreads();   // xsT + hbuf init visible

    // x-offset quad registers: qA covers steps 8k..8k+3, qB 8k+4..8k+7.
    int4 qA = *(const int4*)&xsT[r][0];
    int4 qB = *(const int4*)&xsT[r][4];
    float4 X0 = *(const float4*)(tabB + (u32)qA.x + joff);   // step-0 x-term
    float4 X1;

    auto stepf = [&](int p, const float4 Xc, float4& Xn, u32 e) {
        __builtin_amdgcn_s_setprio(1);   // latency-critical head
        const u16* rh = &hbuf[p][0][0];
        u16* wh = &hbuf[p ^ 1][0][0];
        bf16x8 Ah0 = *(const bf16x8*)(rh + aoff);         // k 0..31
        bf16x8 Ah1 = *(const bf16x8*)(rh + aoff + 32);    // k 32..63

        // issue x-term load for next step (vmcnt wait lands at next use)
        Xn = *(const float4*)(tabB + e + joff);

        // 8 gate tiles (4 gates x 2 n-slices), K=64 in 2 chunks
        f32x4 acc[4][2];
#pragma unroll
        for (int g = 0; g < 4; ++g)
#pragma unroll
            for (int n = 0; n < 2; ++n)
                acc[g][n] = __builtin_amdgcn_mfma_f32_16x16x32_bf16(
                    Ah0, Bg[g][n][0], z4, 0, 0, 0);
#pragma unroll
        for (int g = 0; g < 4; ++g)
#pragma unroll
            for (int n = 0; n < 2; ++n)
                acc[g][n] = __builtin_amdgcn_mfma_f32_16x16x32_bf16(
                    Ah1, Bg[g][n][1], acc[g][n], 0, 0, 0);

        // lane-local gates: all 4 C-regs duplicate real row q>>1; pick the
        // n-tile matching my j by (q&1) — one cndmask per gate.
        const bool s = (q & 1);
        float gi = (s ? acc[0][1][0] : acc[0][0][0]) + Xc.x;
        float gf = (s ? acc[1][1][0] : acc[1][0][0]) + Xc.y;
        float gg = (s ? acc[2][1][0] : acc[2][0][0]) + Xc.z;
        float go = (s ? acc[3][1][0] : acc[3][0][0]) + Xc.w;
        __builtin_amdgcn_s_setprio(0);   // latency-tolerant tail

        cc   = sigmoid_f(gf) * cc + sigmoid_f(gi) * tanh_f(gg);
        hcur = sigmoid_f(go) * tanh_f(cc);

        u32 hb;   // RNE f32->bf16, single instruction (== f2bf_rne bits)
        asm("v_cvt_pk_bf16_f32 %0, %1, %2" : "=v"(hb) : "v"(hcur), "v"(hcur));
        wh[woff] = (u16)hb;

        barrier_lgkm();
    };

    for (int kk = 0; kk < T_STEPS / 8; ++kk) {
        stepf(0, X0, X1, (u32)qA.y);
        stepf(1, X1, X0, (u32)qA.z);
        stepf(0, X0, X1, (u32)qA.w);
        qA = *(const int4*)&xsT[r][8 * kk + 8];       // steps 8kk+8..11
        stepf(1, X1, X0, (u32)qB.x);
        stepf(0, X0, X1, (u32)qB.y);
        stepf(1, X1, X0, (u32)qB.z);
        stepf(0, X0, X1, (u32)qB.w);
        qB = *(const int4*)&xsT[r][8 * kk + 12];      // steps 8kk+12..15
        stepf(1, X1, X0, (u32)qA.x);
    }

    // every lane owns exactly one (b_base+r, jj)
    hfin[(dir * BATCH + b_base + r) * HH + jj] = hcur;
}

// ---------------- Kernel 3: final FC (W_fc in LDS, 8 rows/block) ----------
__global__ __launch_bounds__(256) void fc_kernel(
    const float* __restrict__ hfin,    // [2][1024][64]
    const float* __restrict__ W_fc,    // [128][128]
    const float* __restrict__ b_fc,    // [128]
    float* __restrict__ out)           // [1024][128]
{
    __shared__ float wfc[HID * 129];   // row-padded: bank stride 129
    __shared__ float hid[8][HID];
    const int tid = threadIdx.x;
    const int b0  = blockIdx.x * 8;

    for (int i = tid; i < HID * HID; i += 256) {
        int r = i >> 7, c = i & 127;
        wfc[r * 129 + c] = W_fc[i];
    }
    for (int i = tid; i < 8 * HID; i += 256) {
        int bb = i >> 7, v = i & 127;
        hid[bb][v] = (v < HH) ? hfin[(0 * BATCH + b0 + bb) * HH + v]
                              : hfin[(1 * BATCH + b0 + bb) * HH + (v - HH)];
    }
    __syncthreads();

    const int v  = tid & 127;
    const int bs = (tid >> 7) * 4;     // rows [bs, bs+4)
    const float bias = b_fc[v];
    const float* wrow = wfc + v * 129;
#pragma unroll
    for (int r = 0; r < 4; ++r) {
        const float* h = hid[bs + r];
        float acc = bias;
#pragma unroll
        for (int k = 0; k < HID; k += 4) {
            acc += wrow[k]     * h[k]     + wrow[k + 1] * h[k + 1]
                 + wrow[k + 2] * h[k + 2] + wrow[k + 3] * h[k + 3];
        }
        out[(b0 + bs + r) * HID + v] = acc;
    }
}

extern "C" void kernel_launch(void* const* d_in, const int* in_sizes, int n_in,
                              void* d_out, int out_size, void* d_ws, size_t ws_size,
                              hipStream_t stream) {
    const int*   x      = (const int*)d_in[0];
    // d_in[1] = lengths : unused by the reference
    const float* emb    = (const float*)d_in[2];
    const float* W_ih_f = (const float*)d_in[3];
    const float* W_hh_f = (const float*)d_in[4];
    const float* W_ih_b = (const float*)d_in[5];
    const float* W_hh_b = (const float*)d_in[6];
    const float* W_fc   = (const float*)d_in[7];
    const float* b_fc   = (const float*)d_in[8];
    float* out = (float*)d_out;

    float* tab3   = (float*)d_ws;                         // 65536 f32
    u16*   whh_bf = (u16*)(tab3 + 2 * VOCAB * NG);        // 32768 u16
    float* hfin   = (float*)(whh_bf + 2 * NG * HH);       // 131072 f32

    build_tab_kernel<<<dim3(VOCAB, 2), 256, 0, stream>>>(
        emb, W_ih_f, W_ih_b, W_hh_f, W_hh_b, tab3, whh_bf);
    lstm_rec_kernel<<<dim3(BATCH / MB, 2), 128, 0, stream>>>(x, whh_bf, tab3, hfin);
    fc_kernel<<<dim3(BATCH / 8), 256, 0, stream>>>(hfin, W_fc, b_fc, out);
}